// Round 1
// baseline (215.750 us; speedup 1.0000x reference)
//
#include <hip/hip_runtime.h>

// PatchAttacker: B=32 images 512x512x3, N=6 boxes, patch 512x512x3.
// Final pixel = bilinear(patch) of the LAST valid covering patch box, else image.
// v2: 4 pixels per thread (48 B = 3x float4) -> fully-coalesced dwordx4 VMEM,
//     box geometry + bilinear row setup amortized/hoisted across the 4 pixels.

#define Bn 32
#define Nn 6
#define Hh 512
#define Ww 512
#define Pp 512

typedef float f32x4 __attribute__((ext_vector_type(4)));

__global__ __launch_bounds__(256) void patch_attack_kernel(
    const float* __restrict__ images,  // [B,H,W,3]
    const float* __restrict__ boxes,   // [B,N,4] (ymin,xmin,ymax,xmax)
    const float* __restrict__ patch,   // [P,P,3]
    float* __restrict__ out)           // [B,H,W,3]
{
    // Each thread owns a 4-pixel chunk (one row, x..x+3): 48 B contiguous.
    const int chunk = blockIdx.x * 256 + threadIdx.x;     // 2,097,152 chunks
    const int b     = chunk >> 16;                        // 65536 chunks / image
    const int rem   = chunk & 65535;
    const int y     = rem >> 7;                           // 128 chunks / row
    const int x4    = (rem & 127) << 2;                   // starting x of chunk

    const float* __restrict__ bx = boxes + (size_t)b * Nn * 4;

    float r[12];
    bool cov[4] = {false, false, false, false};

    // descending n: first valid covering box == last writer in the reference scan
    #pragma unroll
    for (int n = Nn - 1; n >= 0; --n) {
        const float ymin = bx[n * 4 + 0];
        const float xmin = bx[n * 4 + 1];
        const float ymax = bx[n * 4 + 2];
        const float xmax = bx[n * 4 + 3];
        const float h  = ymax - ymin;
        const float w  = xmax - xmin;
        const float pw = h * 0.5f;            // SCALE = 0.5
        const float ph = 1.0f * pw;           // ASPECT = 1.0
        const float oy = ymin + h * 0.5f;
        const float ox = xmin + w * 0.5f;
        float yp = fmaxf(oy - ph * 0.5f, 0.0f);
        float xp = fmaxf(ox - pw * 0.5f, 0.0f);
        yp = (yp + ph > (float)Hh) ? ((float)Hh - ph) : yp;
        xp = (xp + pw > (float)Ww) ? ((float)Ww - pw) : xp;
        const bool valid = ph > 60.0f;        // MIN_PH

        // tf.cast truncation; all quantities >= 0 so C cast matches
        const int y0b = (int)yp;
        const int x0b = (int)xp;
        const int hI  = (int)ph;
        const int wI  = (int)pw;
        const int dy  = y - y0b;

        if (!(valid && dy >= 0 && dy < hI)) continue;   // row not covered by box n

        // --- row-uniform bilinear setup (shared by all 4 pixels) ---
        const float hf = (float)(hI > 1 ? hI : 1);
        const float wf = (float)(wI > 1 ? wI : 1);
        float sy = ((float)dy + 0.5f) * ((float)Pp / hf) - 0.5f;
        sy = fminf(fmaxf(sy, 0.0f), (float)(Pp - 1));
        const int   yl = (int)floorf(sy);
        const int   yh = (yl + 1 < Pp - 1) ? (yl + 1) : (Pp - 1);
        const float wy = sy - (float)yl;
        const float omwy = 1.0f - wy;
        const float winv = (float)Pp / wf;
        const float* __restrict__ rowl = patch + (size_t)yl * (Pp * 3);
        const float* __restrict__ rowh = patch + (size_t)yh * (Pp * 3);

        #pragma unroll
        for (int j = 0; j < 4; ++j) {
            if (cov[j]) continue;
            const int dx = x4 + j - x0b;
            if (dx < 0 || dx >= wI) continue;

            float sx = ((float)dx + 0.5f) * winv - 0.5f;
            sx = fminf(fmaxf(sx, 0.0f), (float)(Pp - 1));
            const int   xl = (int)floorf(sx);
            const int   xh = (xl + 1 < Pp - 1) ? (xl + 1) : (Pp - 1);
            const float wx = sx - (float)xl;
            const float omwx = 1.0f - wx;

            const float* __restrict__ pll = rowl + xl * 3;
            const float* __restrict__ plh = rowl + xh * 3;
            const float* __restrict__ phl = rowh + xl * 3;
            const float* __restrict__ phh = rowh + xh * 3;
            // separable bilinear, same op order as reference (rows over y, then x)
            r[j * 3 + 0] = (pll[0] * omwy + phl[0] * wy) * omwx + (plh[0] * omwy + phh[0] * wy) * wx;
            r[j * 3 + 1] = (pll[1] * omwy + phl[1] * wy) * omwx + (plh[1] * omwy + phh[1] * wy) * wx;
            r[j * 3 + 2] = (pll[2] * omwy + phl[2] * wy) * omwx + (plh[2] * omwy + phh[2] * wy) * wx;
            cov[j] = true;
        }
        if (cov[0] & cov[1] & cov[2] & cov[3]) break;   // all 4 pixels resolved
    }

    // Fallback to the source image for uncovered pixels (one vectorized load).
    if (!(cov[0] & cov[1] & cov[2] & cov[3])) {
        const f32x4* __restrict__ ip =
            (const f32x4*)(images + (size_t)chunk * 12);
        const f32x4 i0 = __builtin_nontemporal_load(ip + 0);
        const f32x4 i1 = __builtin_nontemporal_load(ip + 1);
        const f32x4 i2 = __builtin_nontemporal_load(ip + 2);
        const float img[12] = {i0.x, i0.y, i0.z, i0.w,
                               i1.x, i1.y, i1.z, i1.w,
                               i2.x, i2.y, i2.z, i2.w};
        #pragma unroll
        for (int j = 0; j < 4; ++j) {
            if (!cov[j]) {
                r[j * 3 + 0] = img[j * 3 + 0];
                r[j * 3 + 1] = img[j * 3 + 1];
                r[j * 3 + 2] = img[j * 3 + 2];
            }
        }
    }

    f32x4* __restrict__ op = (f32x4*)(out + (size_t)chunk * 12);
    f32x4 o0, o1, o2;
    o0.x = r[0];  o0.y = r[1];  o0.z = r[2];  o0.w = r[3];
    o1.x = r[4];  o1.y = r[5];  o1.z = r[6];  o1.w = r[7];
    o2.x = r[8];  o2.y = r[9];  o2.z = r[10]; o2.w = r[11];
    __builtin_nontemporal_store(o0, op + 0);
    __builtin_nontemporal_store(o1, op + 1);
    __builtin_nontemporal_store(o2, op + 2);
}

extern "C" void kernel_launch(void* const* d_in, const int* in_sizes, int n_in,
                              void* d_out, int out_size, void* d_ws, size_t ws_size,
                              hipStream_t stream) {
    const float* images = (const float*)d_in[0];
    const float* boxes  = (const float*)d_in[1];
    const float* patch  = (const float*)d_in[2];
    float* out = (float*)d_out;

    const int total_chunks = Bn * Hh * Ww / 4;  // 2,097,152
    const int block = 256;
    const int grid  = total_chunks / block;     // 8192

    patch_attack_kernel<<<grid, block, 0, stream>>>(images, boxes, patch, out);
}

// Round 2
// 209.658 us; speedup vs baseline: 1.0291x; 1.0291x over previous
//
#include <hip/hip_runtime.h>

// PatchAttacker: B=32 images 512x512x3, N=6 boxes, patch 512x512x3.
// Final pixel = bilinear(patch) of the LAST valid covering patch box, else image.
// v3: v2 compute (4 px/thread, amortized box math) + LDS block-transpose on the
//     store path so every global store instruction is lane-dense (full 128B
//     lines) -> non-temporal stores are safe (no partial-line write
//     amplification, no L2 pollution; L2 stays dedicated to the 3MB patch).

#define Bn 32
#define Nn 6
#define Hh 512
#define Ww 512
#define Pp 512

typedef float f32x4 __attribute__((ext_vector_type(4)));

__global__ __launch_bounds__(256) void patch_attack_kernel(
    const float* __restrict__ images,  // [B,H,W,3]
    const float* __restrict__ boxes,   // [B,N,4] (ymin,xmin,ymax,xmax)
    const float* __restrict__ patch,   // [P,P,3]
    float* __restrict__ out)           // [B,H,W,3]
{
    // 12 KB: 256 threads x 12 floats (4 pixels each), flat block-output layout.
    __shared__ float lds[3072];

    const int tid   = threadIdx.x;
    const int chunk = blockIdx.x * 256 + tid;             // 2,097,152 chunks
    const int b     = chunk >> 16;                        // 65536 chunks / image
    const int rem   = chunk & 65535;
    const int y     = rem >> 7;                           // 128 chunks / row
    const int x4    = (rem & 127) << 2;                   // starting x of chunk

    const float* __restrict__ bx = boxes + (size_t)b * Nn * 4;

    float r[12];
    bool cov[4] = {false, false, false, false};

    // descending n: first valid covering box == last writer in the reference scan
    #pragma unroll
    for (int n = Nn - 1; n >= 0; --n) {
        const float ymin = bx[n * 4 + 0];
        const float xmin = bx[n * 4 + 1];
        const float ymax = bx[n * 4 + 2];
        const float xmax = bx[n * 4 + 3];
        const float h  = ymax - ymin;
        const float w  = xmax - xmin;
        const float pw = h * 0.5f;            // SCALE = 0.5
        const float ph = 1.0f * pw;           // ASPECT = 1.0
        const float oy = ymin + h * 0.5f;
        const float ox = xmin + w * 0.5f;
        float yp = fmaxf(oy - ph * 0.5f, 0.0f);
        float xp = fmaxf(ox - pw * 0.5f, 0.0f);
        yp = (yp + ph > (float)Hh) ? ((float)Hh - ph) : yp;
        xp = (xp + pw > (float)Ww) ? ((float)Ww - pw) : xp;
        const bool valid = ph > 60.0f;        // MIN_PH

        // tf.cast truncation; all quantities >= 0 so C cast matches
        const int y0b = (int)yp;
        const int x0b = (int)xp;
        const int hI  = (int)ph;
        const int wI  = (int)pw;
        const int dy  = y - y0b;

        if (!(valid && dy >= 0 && dy < hI)) continue;   // row not covered by box n

        // --- row-uniform bilinear setup (shared by all 4 pixels) ---
        const float hf = (float)(hI > 1 ? hI : 1);
        const float wf = (float)(wI > 1 ? wI : 1);
        float sy = ((float)dy + 0.5f) * ((float)Pp / hf) - 0.5f;
        sy = fminf(fmaxf(sy, 0.0f), (float)(Pp - 1));
        const int   yl = (int)floorf(sy);
        const int   yh = (yl + 1 < Pp - 1) ? (yl + 1) : (Pp - 1);
        const float wy = sy - (float)yl;
        const float omwy = 1.0f - wy;
        const float winv = (float)Pp / wf;
        const float* __restrict__ rowl = patch + (size_t)yl * (Pp * 3);
        const float* __restrict__ rowh = patch + (size_t)yh * (Pp * 3);

        #pragma unroll
        for (int j = 0; j < 4; ++j) {
            if (cov[j]) continue;
            const int dx = x4 + j - x0b;
            if (dx < 0 || dx >= wI) continue;

            float sx = ((float)dx + 0.5f) * winv - 0.5f;
            sx = fminf(fmaxf(sx, 0.0f), (float)(Pp - 1));
            const int   xl = (int)floorf(sx);
            const int   xh = (xl + 1 < Pp - 1) ? (xl + 1) : (Pp - 1);
            const float wx = sx - (float)xl;
            const float omwx = 1.0f - wx;

            const float* __restrict__ pll = rowl + xl * 3;
            const float* __restrict__ plh = rowl + xh * 3;
            const float* __restrict__ phl = rowh + xl * 3;
            const float* __restrict__ phh = rowh + xh * 3;
            // separable bilinear, same op order as reference (rows over y, then x)
            r[j * 3 + 0] = (pll[0] * omwy + phl[0] * wy) * omwx + (plh[0] * omwy + phh[0] * wy) * wx;
            r[j * 3 + 1] = (pll[1] * omwy + phl[1] * wy) * omwx + (plh[1] * omwy + phh[1] * wy) * wx;
            r[j * 3 + 2] = (pll[2] * omwy + phl[2] * wy) * omwx + (plh[2] * omwy + phh[2] * wy) * wx;
            cov[j] = true;
        }
        if (cov[0] & cov[1] & cov[2] & cov[3]) break;   // all 4 pixels resolved
    }

    // Fallback to the source image for uncovered pixels (vectorized nt load).
    if (!(cov[0] & cov[1] & cov[2] & cov[3])) {
        const f32x4* __restrict__ ip =
            (const f32x4*)(images + (size_t)chunk * 12);
        const f32x4 i0 = __builtin_nontemporal_load(ip + 0);
        const f32x4 i1 = __builtin_nontemporal_load(ip + 1);
        const f32x4 i2 = __builtin_nontemporal_load(ip + 2);
        const float img[12] = {i0.x, i0.y, i0.z, i0.w,
                               i1.x, i1.y, i1.z, i1.w,
                               i2.x, i2.y, i2.z, i2.w};
        #pragma unroll
        for (int j = 0; j < 4; ++j) {
            if (!cov[j]) {
                r[j * 3 + 0] = img[j * 3 + 0];
                r[j * 3 + 1] = img[j * 3 + 1];
                r[j * 3 + 2] = img[j * 3 + 2];
            }
        }
    }

    // --- LDS block-transpose: [thread][12] -> flat block-output order ---
    // Write side: 3x ds_write_b128 at 48B lane stride (start banks {0,4,..,28}
    // per 8-lane phase -> conflict-free).
    f32x4* __restrict__ lw = (f32x4*)(lds + tid * 12);
    f32x4 w0, w1, w2;
    w0.x = r[0];  w0.y = r[1];  w0.z = r[2];  w0.w = r[3];
    w1.x = r[4];  w1.y = r[5];  w1.z = r[6];  w1.w = r[7];
    w2.x = r[8];  w2.y = r[9];  w2.z = r[10]; w2.w = r[11];
    lw[0] = w0;
    lw[1] = w1;
    lw[2] = w2;

    __syncthreads();

    // Read side: contiguous b128 (conflict-free). Store side: each wave-instr
    // writes a dense, 128B-aligned 1024B segment -> full-line nt stores.
    const size_t blk_f = (size_t)blockIdx.x * 3072;
    #pragma unroll
    for (int k = 0; k < 3; ++k) {
        const f32x4 v = *(const f32x4*)(lds + k * 1024 + tid * 4);
        __builtin_nontemporal_store(
            v, (f32x4*)(out + blk_f + (size_t)k * 1024 + (size_t)tid * 4));
    }
}

extern "C" void kernel_launch(void* const* d_in, const int* in_sizes, int n_in,
                              void* d_out, int out_size, void* d_ws, size_t ws_size,
                              hipStream_t stream) {
    const float* images = (const float*)d_in[0];
    const float* boxes  = (const float*)d_in[1];
    const float* patch  = (const float*)d_in[2];
    float* out = (float*)d_out;

    const int total_chunks = Bn * Hh * Ww / 4;  // 2,097,152
    const int block = 256;
    const int grid  = total_chunks / block;     // 8192

    patch_attack_kernel<<<grid, block, 0, stream>>>(images, boxes, patch, out);
}

// Round 4
// 198.170 us; speedup vs baseline: 1.0887x; 1.0580x over previous
//
#include <hip/hip_runtime.h>

// PatchAttacker: B=32 images 512x512x3, N=6 boxes, patch 512x512x3.
// Final pixel = bilinear(patch) of the LAST valid covering patch box, else image.
// v4b: latency-oriented restructure (resubmit of v4 after infra failure, with
//      gather loads hardened to explicitly-4B-aligned typed loads).
//   - Pass 1: branch-light coverage resolution; per-pixel covering-box id plus
//     saved gather offsets/weights (no memory ops). y,b are wave-uniform ->
//     readfirstlane to SGPR; whole-box row rejection is a uniform branch.
//   - Image loads (nt, predicated) issued RIGHT AFTER coverage is known,
//     consumed at the very end -> ~900cy cold-HBM latency hidden under pass 2.
//   - Pass 2: all 4 pixels' patch-row loads issued together (two contiguous
//     24B loads per pixel; xl clamped to 510 so low/high columns merge),
//     consumed after -> 8 independent gathers in flight per thread.
//   - Store path unchanged from v3: LDS block-transpose -> full-line nt stores
//     (WRITE_SIZE == exact output, verified in v3 counters).

#define Bn 32
#define Nn 6
#define Hh 512
#define Ww 512
#define Pp 512

typedef float f32x4 __attribute__((ext_vector_type(4)));
typedef float f32x4u __attribute__((ext_vector_type(4), aligned(4)));
typedef float f32x2u __attribute__((ext_vector_type(2), aligned(4)));

__global__ __launch_bounds__(256) void patch_attack_kernel(
    const float* __restrict__ images,  // [B,H,W,3]
    const float* __restrict__ boxes,   // [B,N,4] (ymin,xmin,ymax,xmax)
    const float* __restrict__ patch,   // [P,P,3]
    float* __restrict__ out)           // [B,H,W,3]
{
    __shared__ float lds[3072];        // 256 threads x 12 floats

    const int tid   = threadIdx.x;
    const int chunk = blockIdx.x * 256 + tid;             // 4-pixel chunks
    // b uniform per block, y uniform per wave (wave = 64 chunks = half a row)
    const int b     = __builtin_amdgcn_readfirstlane(chunk >> 16);
    const int rem   = chunk & 65535;
    const int y     = __builtin_amdgcn_readfirstlane(rem >> 7);
    const int x4    = (rem & 127) << 2;                   // starting x of chunk

    const float* __restrict__ bx = boxes + b * (Nn * 4);

    // ---------------- pass 1: coverage resolution (no loads) ----------------
    int   bid[4]  = {-1, -1, -1, -1};
    int   offL[4] = {0, 0, 0, 0};      // byte offset of low-row 6-float group
    float wxs[4]  = {0.f, 0.f, 0.f, 0.f};
    float wys[4]  = {0.f, 0.f, 0.f, 0.f};

    #pragma unroll
    for (int n = Nn - 1; n >= 0; --n) {   // descending: first hit == last writer
        const float ymin = bx[n * 4 + 0];
        const float xmin = bx[n * 4 + 1];
        const float ymax = bx[n * 4 + 2];
        const float xmax = bx[n * 4 + 3];
        const float h  = ymax - ymin;
        const float w  = xmax - xmin;
        const float pw = h * 0.5f;            // SCALE = 0.5
        const float ph = 1.0f * pw;           // ASPECT = 1.0
        const float oy = ymin + h * 0.5f;
        const float ox = xmin + w * 0.5f;
        float yp = fmaxf(oy - ph * 0.5f, 0.0f);
        float xp = fmaxf(ox - pw * 0.5f, 0.0f);
        yp = (yp + ph > (float)Hh) ? ((float)Hh - ph) : yp;
        xp = (xp + pw > (float)Ww) ? ((float)Ww - pw) : xp;
        const bool valid = ph > 60.0f;        // MIN_PH

        const int y0b = (int)yp;              // tf.cast truncation (>=0)
        const int x0b = (int)xp;
        const int hI  = (int)ph;
        const int wI  = (int)pw;
        const int dy  = y - y0b;

        // wave-uniform rejection (y is SGPR): skips ~75% of boxes per wave
        if (!(valid && dy >= 0 && dy < hI)) continue;

        const float hf = (float)(hI > 1 ? hI : 1);
        const float wf = (float)(wI > 1 ? wI : 1);
        float sy = ((float)dy + 0.5f) * ((float)Pp / hf) - 0.5f;
        sy = fminf(fmaxf(sy, 0.0f), (float)(Pp - 1));
        int yl = (int)sy;                     // == floor (sy >= 0)
        yl = (yl > Pp - 2) ? (Pp - 2) : yl;   // clamp so yh = yl+1 always;
        const float wyv = sy - (float)yl;     // wy==1 picks row 511 exactly
        const float winv = (float)Pp / wf;
        const int rl = yl * (Pp * 3 * 4);     // row byte offset (6144 B/row)

        #pragma unroll
        for (int j = 0; j < 4; ++j) {
            const int dx = x4 + j - x0b;
            float sx = ((float)dx + 0.5f) * winv - 0.5f;
            sx = fminf(fmaxf(sx, 0.0f), (float)(Pp - 1));
            int xl = (int)sx;
            xl = (xl > Pp - 2) ? (Pp - 2) : xl;   // xh = xl+1 always; wx==1 -> col 511
            const float wxv = sx - (float)xl;
            const bool hit = (dx >= 0) & (dx < wI) & (bid[j] < 0);
            if (hit) {                 // select chains, no divergence cost
                bid[j]  = n;
                offL[j] = rl + xl * 12;
                wxs[j]  = wxv;
                wys[j]  = wyv;
            }
        }
    }

    // -------- issue image loads EARLY (consumed at the very end) --------
    const bool c0 = bid[0] >= 0, c1 = bid[1] >= 0, c2 = bid[2] >= 0, c3 = bid[3] >= 0;
    f32x4 i0 = {0.f, 0.f, 0.f, 0.f}, i1 = i0, i2 = i0;
    if (!(c0 & c1 & c2 & c3)) {
        const f32x4* __restrict__ ip = (const f32x4*)(images + (size_t)chunk * 12);
        i0 = __builtin_nontemporal_load(ip + 0);
        i1 = __builtin_nontemporal_load(ip + 1);
        i2 = __builtin_nontemporal_load(ip + 2);
    }

    // ---------------- pass 2: batched patch gathers + bilinear ----------------
    float pr[12] = {0.f, 0.f, 0.f, 0.f, 0.f, 0.f, 0.f, 0.f, 0.f, 0.f, 0.f, 0.f};
    const char* __restrict__ pbytes = (const char*)patch;
    if (__any(c0 | c1 | c2 | c3)) {
        // uncovered lanes read patch[0..24) harmlessly (offL==0).
        // offL is a multiple of 4 -> explicitly 4B-aligned vector loads.
        float A[4][6], Bv[4][6];
        #pragma unroll
        for (int j = 0; j < 4; ++j) {
            const f32x4u a0 = *(const f32x4u*)(pbytes + offL[j]);          // yl: x{l,l+1}
            const f32x2u a1 = *(const f32x2u*)(pbytes + offL[j] + 16);
            const f32x4u b0 = *(const f32x4u*)(pbytes + offL[j] + 6144);   // yl+1
            const f32x2u b1 = *(const f32x2u*)(pbytes + offL[j] + 6160);
            A[j][0] = a0.x;  A[j][1] = a0.y;  A[j][2] = a0.z;
            A[j][3] = a0.w;  A[j][4] = a1.x;  A[j][5] = a1.y;
            Bv[j][0] = b0.x; Bv[j][1] = b0.y; Bv[j][2] = b0.z;
            Bv[j][3] = b0.w; Bv[j][4] = b1.x; Bv[j][5] = b1.y;
        }
        #pragma unroll
        for (int j = 0; j < 4; ++j) {
            const float wyv = wys[j], wxv = wxs[j];
            const float omy = 1.0f - wyv, omx = 1.0f - wxv;
            #pragma unroll
            for (int c = 0; c < 3; ++c) {
                // same op order as reference: rows over y, then x
                pr[j * 3 + c] = (A[j][c]     * omy + Bv[j][c]     * wyv) * omx
                              + (A[j][3 + c] * omy + Bv[j][3 + c] * wyv) * wxv;
            }
        }
    }

    // ---------------- final select (image loads consumed here) ----------------
    const float img[12] = {i0.x, i0.y, i0.z, i0.w,
                           i1.x, i1.y, i1.z, i1.w,
                           i2.x, i2.y, i2.z, i2.w};
    float r[12];
    #pragma unroll
    for (int j = 0; j < 4; ++j) {
        const bool cv = bid[j] >= 0;
        r[j * 3 + 0] = cv ? pr[j * 3 + 0] : img[j * 3 + 0];
        r[j * 3 + 1] = cv ? pr[j * 3 + 1] : img[j * 3 + 1];
        r[j * 3 + 2] = cv ? pr[j * 3 + 2] : img[j * 3 + 2];
    }

    // ---- LDS block-transpose -> full-line nt stores (proven in v3) ----
    f32x4* __restrict__ lw = (f32x4*)(lds + tid * 12);
    f32x4 w0, w1, w2;
    w0.x = r[0];  w0.y = r[1];  w0.z = r[2];  w0.w = r[3];
    w1.x = r[4];  w1.y = r[5];  w1.z = r[6];  w1.w = r[7];
    w2.x = r[8];  w2.y = r[9];  w2.z = r[10]; w2.w = r[11];
    lw[0] = w0;
    lw[1] = w1;
    lw[2] = w2;

    __syncthreads();

    const size_t blk_f = (size_t)blockIdx.x * 3072;
    #pragma unroll
    for (int k = 0; k < 3; ++k) {
        const f32x4 v = *(const f32x4*)(lds + k * 1024 + tid * 4);
        __builtin_nontemporal_store(
            v, (f32x4*)(out + blk_f + (size_t)k * 1024 + (size_t)tid * 4));
    }
}

extern "C" void kernel_launch(void* const* d_in, const int* in_sizes, int n_in,
                              void* d_out, int out_size, void* d_ws, size_t ws_size,
                              hipStream_t stream) {
    const float* images = (const float*)d_in[0];
    const float* boxes  = (const float*)d_in[1];
    const float* patch  = (const float*)d_in[2];
    float* out = (float*)d_out;

    const int total_chunks = Bn * Hh * Ww / 4;  // 2,097,152
    const int block = 256;
    const int grid  = total_chunks / block;     // 8192

    patch_attack_kernel<<<grid, block, 0, stream>>>(images, boxes, patch, out);
}